// Round 12
// baseline (485.941 us; speedup 1.0000x reference)
//
#include <hip/hip_runtime.h>
#include <hip/hip_bf16.h>

typedef __attribute__((ext_vector_type(8))) short bf16x8;
typedef __attribute__((ext_vector_type(4))) float f32x4;
typedef unsigned short u16;

#define D_IN  1024
#define D_HID 4096
#define MROWS 16384   // B*T = 8*2048

// ---------- bf16 <-> f32 helpers (bit-exact RNE) ----------
__device__ __forceinline__ float b2f(u16 u) {
    union { unsigned int i; float f; } c; c.i = ((unsigned int)u) << 16; return c.f;
}
__device__ __forceinline__ u16 f2b(float f) {
    unsigned int u = __builtin_bit_cast(unsigned int, f);
    return (u16)((u + 0x7FFFu + ((u >> 16) & 1u)) >> 16);
}

// ---------- fast branchless GELU (tanh form, err<=3e-3 abs, << bf16 step) ----
__device__ __forceinline__ float gelu_fast(float v) {
    float p = v * fmaf(0.044715f * v, v, 1.0f);
    float e = __builtin_amdgcn_exp2f(-2.302202983f * p);
    return v * __builtin_amdgcn_rcpf(1.0f + e);
}

// ---------- 16-lane (DPP row) sum via row_shr: TOTAL lands in lane&15==15 ----
__device__ __forceinline__ float rowsum16(float v) {
    int t;
    t = __builtin_amdgcn_update_dpp(0, __builtin_bit_cast(int, v), 0x111, 0xf, 0xf, true);
    v += __builtin_bit_cast(float, t);
    t = __builtin_amdgcn_update_dpp(0, __builtin_bit_cast(int, v), 0x112, 0xf, 0xf, true);
    v += __builtin_bit_cast(float, t);
    t = __builtin_amdgcn_update_dpp(0, __builtin_bit_cast(int, v), 0x114, 0xf, 0xf, true);
    v += __builtin_bit_cast(float, t);
    t = __builtin_amdgcn_update_dpp(0, __builtin_bit_cast(int, v), 0x118, 0xf, 0xf, true);
    v += __builtin_bit_cast(float, t);
    return v;   // lane 15 of each 16-lane row holds the full row sum
}

// ---------- prep1: absmean partials for both W (y=0,1) + cast x->bf16 (y=2) ----
__global__ void prep1(const float* __restrict__ x, const float* __restrict__ W0,
                      const float* __restrict__ W1, u16* __restrict__ xb,
                      float* __restrict__ partials, int n4, int n8) {
    const int y = blockIdx.y;
    if (y == 2) {
        const int stride = gridDim.x * blockDim.x;
        for (int i = blockIdx.x * blockDim.x + threadIdx.x; i < n8; i += stride) {
            float4 a = ((const float4*)x)[2 * i];
            float4 c = ((const float4*)x)[2 * i + 1];
            bf16x8 o;
            o[0] = (short)f2b(a.x); o[1] = (short)f2b(a.y); o[2] = (short)f2b(a.z); o[3] = (short)f2b(a.w);
            o[4] = (short)f2b(c.x); o[5] = (short)f2b(c.y); o[6] = (short)f2b(c.z); o[7] = (short)f2b(c.w);
            ((bf16x8*)xb)[i] = o;
        }
        return;
    }
    const float* W = y ? W1 : W0;
    float* out = partials + y * 1024;
    __shared__ float sdata[256];
    float s = 0.f;
    const int stride = gridDim.x * blockDim.x;
    for (int i = blockIdx.x * blockDim.x + threadIdx.x; i < n4; i += stride) {
        float4 v = ((const float4*)W)[i];
        s += fabsf(v.x) + fabsf(v.y) + fabsf(v.z) + fabsf(v.w);
    }
    sdata[threadIdx.x] = s;
    __syncthreads();
    for (int off = 128; off > 0; off >>= 1) {
        if (threadIdx.x < off) sdata[threadIdx.x] += sdata[threadIdx.x + off];
        __syncthreads();
    }
    if (threadIdx.x == 0) out[blockIdx.x] = sdata[0];
}

__global__ void absmean_finalize2(const float* __restrict__ partials, float inv_n,
                                  float* __restrict__ gamma) {
    const float* p = partials + blockIdx.x * 1024;
    __shared__ float sdata[256];
    float s = 0.f;
    for (int i = threadIdx.x; i < 1024; i += 256) s += p[i];
    sdata[threadIdx.x] = s;
    __syncthreads();
    for (int off = 128; off > 0; off >>= 1) {
        if (threadIdx.x < off) sdata[threadIdx.x] += sdata[threadIdx.x + off];
        __syncthreads();
    }
    if (threadIdx.x == 0) gamma[blockIdx.x] = sdata[0] * inv_n + 1e-6f;
}

// ---------- prep2: quant W0 (y=0); quant W1*lnw per-row + fused GEMV (y=1) ----
__global__ void prep2(const float* __restrict__ W0, const float* __restrict__ W1,
                      const float* __restrict__ lnw, const float* __restrict__ lnb,
                      const float* __restrict__ gamma,
                      u16* __restrict__ Q0, u16* __restrict__ Q1,
                      float* __restrict__ c1, float* __restrict__ c0, int n4) {
    const int y = blockIdx.y;
    if (y == 1) {
        // one block per W_proj row: quantize (scaled by lnw) AND reduce c1/c0
        const float thr = 0.5f * gamma[1];
        const int r = blockIdx.x;                    // 0..1023
        const float* row = W1 + (size_t)r * D_HID;
        u16* qrow = Q1 + (size_t)r * D_HID;
        float s1 = 0.f, s0 = 0.f;
#pragma unroll
        for (int k = 0; k < 4; ++k) {
            const int h = threadIdx.x * 4 + k * 1024;
            float4 v = *(const float4*)(row + h);
            float w0 = lnw[h], w1 = lnw[h + 1], w2 = lnw[h + 2], w3 = lnw[h + 3];
            float b0 = lnb[h], b1 = lnb[h + 1], b2 = lnb[h + 2], b3 = lnb[h + 3];
            float t0 = v.x > thr ? 1.f : (v.x < -thr ? -1.f : 0.f);
            float t1 = v.y > thr ? 1.f : (v.y < -thr ? -1.f : 0.f);
            float t2 = v.z > thr ? 1.f : (v.z < -thr ? -1.f : 0.f);
            float t3 = v.w > thr ? 1.f : (v.w < -thr ? -1.f : 0.f);
            ushort4 q;
            q.x = t0 == 0.f ? 0u : f2b(t0 * w0);
            q.y = t1 == 0.f ? 0u : f2b(t1 * w1);
            q.z = t2 == 0.f ? 0u : f2b(t2 * w2);
            q.w = t3 == 0.f ? 0u : f2b(t3 * w3);
            *(ushort4*)(qrow + h) = q;
            s1 += w0 * t0 + w1 * t1 + w2 * t2 + w3 * t3;
            s0 += b0 * t0 + b1 * t1 + b2 * t2 + b3 * t3;
        }
#pragma unroll
        for (int off = 32; off > 0; off >>= 1) {
            s1 += __shfl_down(s1, off);
            s0 += __shfl_down(s0, off);
        }
        __shared__ float sh1[4], sh0[4];
        const int wave = threadIdx.x >> 6, lane = threadIdx.x & 63;
        if (lane == 0) { sh1[wave] = s1; sh0[wave] = s0; }
        __syncthreads();
        if (threadIdx.x == 0) {
            c1[r] = sh1[0] + sh1[1] + sh1[2] + sh1[3];
            c0[r] = sh0[0] + sh0[1] + sh0[2] + sh0[3];
        }
        return;
    }
    // y == 0: plain ternary quant of W_fc
    const float thr = 0.5f * gamma[0];
    const int stride = gridDim.x * blockDim.x;
    for (int i = blockIdx.x * blockDim.x + threadIdx.x; i < n4; i += stride) {
        float4 v = ((const float4*)W0)[i];
        ushort4 q;
        q.x = v.x > thr ? 0x3F80u : (v.x < -thr ? 0xBF80u : 0u);
        q.y = v.y > thr ? 0x3F80u : (v.y < -thr ? 0xBF80u : 0u);
        q.z = v.z > thr ? 0x3F80u : (v.z < -thr ? 0xBF80u : 0u);
        q.w = v.w > thr ? 0x3F80u : (v.w < -thr ? 0xBF80u : 0u);
        ((ushort4*)Q0)[i] = q;
    }
}

// ==========================================================================
// 256x256 8-phase GEMM, persistent over NT M-tiles per block (same bx).
// At each non-final tile's last ITER (F=2), the stage slots prefetch the
// NEXT tile's A(0)/B(0) into buf0; B(1)->buf1 is issued during the epilogue
// so the epilogue work hides the next prologue's HBM latency.
// EPI 0: GELU -> bf16 out + per-row (sumG,sumG2) via DPP rowsum -> pS/pSS.
// EPI 1: fused-LN epilogue from pS/pSS: out = rstd*acc + (-mu*rstd)*c1 + c0.
// LDS: 128 KiB staging (2 bufs) + 8 KiB epilogue scratch at +131072.
// ==========================================================================
template <int EPI, int NT>
__global__ __launch_bounds__(512, 2)
void gemm256(const u16* __restrict__ A, const u16* __restrict__ B,
             void* __restrict__ Cout, int M, int N, int K, int nbx,
             float* __restrict__ pS, float* __restrict__ pSS,
             const float* __restrict__ c1t, const float* __restrict__ c0t)
{
    (void)M;
    __shared__ char ldsbuf[139264];      // 128 KiB staging + 8 KiB scratch
    char* const ldsc = ldsbuf;
    const int tid = threadIdx.x;
    const int w = tid >> 6, lane = tid & 63;

    // bijective XCD swizzle (nwg % 8 == 0 for our grids)
    const int nwg = (int)gridDim.x;
    const int qq = nwg >> 3;
    const int bid = (int)blockIdx.x;
    const int swz = (bid & 7) * qq + (bid >> 3);
    const int bx = swz % nbx, tg = swz / nbx;
    const size_t n0 = (size_t)bx * 256;

    const int wm = (w >> 2) * 128;       // 0 or 128
    const int wn = (w & 3) * 64;         // 0,64,128,192

    // ---- staging constants: thread tid covers LDS bytes [tid*16,+16) of a half
    const int d0 = tid * 16;
    const int rrow = (d0 >> 6) & 15;
    const int sr0 = ((d0 >> 11) & 3) * 16 + rrow;                 // 0..63 (load1: +64)
    const int cbx = (d0 & 63) ^ (((rrow >> 3) & 1) << 5);         // inverse swizzle on source
    const int gc  = ((d0 >> 10) & 1) * 32 + (cbx >> 1);           // global element col 0..63

    // ---- fragment-read bases (swizzle folded into lane offset)
    const int laneoffsw = (((lane & 15) * 64) + ((lane >> 4) * 16)) ^ (((lane >> 3) & 1) << 5);
    const int aoff = ((wm >> 7) << 14) + laneoffsw;
    const int boff = 65536 + ((wn >> 7) << 14) + (((wn >> 4) & 7) << 11) + laneoffsw;

    f32x4 acc[8][4];
    bf16x8 a[4][2], b[4][2];

#define STAGE_A(KT, BUFB, HH) do {                                                              \
    const u16* _s = A + (size_t)(m0 + (HH) * 128 + sr0) * K + (size_t)(KT) * 64 + gc;           \
    __builtin_amdgcn_global_load_lds((const __attribute__((address_space(1))) void*)_s,         \
        (__attribute__((address_space(3))) void*)(ldsc + (BUFB) * 32768 + (HH) * 16384 + w * 1024), 16, 0, 0); \
    __builtin_amdgcn_global_load_lds((const __attribute__((address_space(1))) void*)(_s + (size_t)64 * K), \
        (__attribute__((address_space(3))) void*)(ldsc + (BUFB) * 32768 + (HH) * 16384 + w * 1024 + 8192), 16, 0, 0); \
} while (0)

#define STAGE_A_N(KT, BUFB, HH) do {                                                            \
    const u16* _s = A + (size_t)(m0n + (HH) * 128 + sr0) * K + (size_t)(KT) * 64 + gc;          \
    __builtin_amdgcn_global_load_lds((const __attribute__((address_space(1))) void*)_s,         \
        (__attribute__((address_space(3))) void*)(ldsc + (BUFB) * 32768 + (HH) * 16384 + w * 1024), 16, 0, 0); \
    __builtin_amdgcn_global_load_lds((const __attribute__((address_space(1))) void*)(_s + (size_t)64 * K), \
        (__attribute__((address_space(3))) void*)(ldsc + (BUFB) * 32768 + (HH) * 16384 + w * 1024 + 8192), 16, 0, 0); \
} while (0)

#define STAGE_B(KT, BUFB, HH) do {                                                              \
    const u16* _s = B + (size_t)(n0 + (HH) * 128 + sr0) * K + (size_t)(KT) * 64 + gc;           \
    __builtin_amdgcn_global_load_lds((const __attribute__((address_space(1))) void*)_s,         \
        (__attribute__((address_space(3))) void*)(ldsc + 65536 + (BUFB) * 32768 + (HH) * 16384 + w * 1024), 16, 0, 0); \
    __builtin_amdgcn_global_load_lds((const __attribute__((address_space(1))) void*)(_s + (size_t)64 * K), \
        (__attribute__((address_space(3))) void*)(ldsc + 65536 + (BUFB) * 32768 + (HH) * 16384 + w * 1024 + 8192), 16, 0, 0); \
} while (0)

#define RD_A(BUFB, S, KS) (*(const bf16x8*)(ldsc + (BUFB) * 32768 + aoff + ((S) << 11) + ((KS) << 10)))
#define RD_B(BUFB, S, KS) (*(const bf16x8*)(ldsc + (BUFB) * 32768 + boff + ((S) << 11) + ((KS) << 10)))

#define MM(MB, NB) do {                                                                         \
    _Pragma("unroll") for (int ii = 0; ii < 4; ++ii)                                            \
    _Pragma("unroll") for (int jj = 0; jj < 2; ++jj)                                            \
    _Pragma("unroll") for (int kk = 0; kk < 2; ++kk)                                            \
        acc[(MB) + ii][(NB) + jj] = __builtin_amdgcn_mfma_f32_16x16x32_bf16(                    \
            a[ii][kk], b[(NB) + jj][kk], acc[(MB) + ii][(NB) + jj], 0, 0, 0);                   \
} while (0)

#define BARR()  asm volatile("s_barrier" ::: "memory")
#define LGKM0() asm volatile("s_waitcnt lgkmcnt(0)" ::: "memory")

// F==1: steady (stage t+2/t+3).  F==2: tile transition (stage next tile's
// A(0)/B(0) -> buf0 in ph5-8).  F==0: very last iteration (no stages).
#define ITER(F) do {                                                                            \
    _Pragma("unroll") for (int s = 0; s < 4; ++s) { a[s][0] = RD_A(0, s, 0); a[s][1] = RD_A(0, s, 1); } \
    _Pragma("unroll") for (int s = 0; s < 2; ++s) { b[s][0] = RD_B(0, s, 0); b[s][1] = RD_B(0, s, 1); } \
    STAGE_A(t + 1, 1, 0);                                                                       \
    asm volatile("s_waitcnt lgkmcnt(8)" ::: "memory");                                          \
    BARR(); LGKM0();                                                                            \
    __builtin_amdgcn_s_setprio(1); MM(0, 0); __builtin_amdgcn_s_setprio(0); BARR();             \
    _Pragma("unroll") for (int s = 2; s < 4; ++s) { b[s][0] = RD_B(0, s, 0); b[s][1] = RD_B(0, s, 1); } \
    STAGE_A(t + 1, 1, 1);                                                                       \
    BARR(); LGKM0();                                                                            \
    __builtin_amdgcn_s_setprio(1); MM(0, 2); __builtin_amdgcn_s_setprio(0); BARR();             \
    _Pragma("unroll") for (int s = 0; s < 4; ++s) { a[s][0] = RD_A(0, 4 + s, 0); a[s][1] = RD_A(0, 4 + s, 1); } \
    if (F == 1) STAGE_B(t + 2, 0, 0);                                                           \
    BARR(); LGKM0();                                                                            \
    __builtin_amdgcn_s_setprio(1); MM(4, 0); __builtin_amdgcn_s_setprio(0); BARR();             \
    if (F == 1) { STAGE_B(t + 2, 0, 1); asm volatile("s_waitcnt vmcnt(4)" ::: "memory"); }      \
    else        { asm volatile("s_waitcnt vmcnt(0)" ::: "memory"); }                            \
    BARR();                                                                                     \
    __builtin_amdgcn_s_setprio(1); MM(4, 2); __builtin_amdgcn_s_setprio(0); BARR();             \
    _Pragma("unroll") for (int s = 0; s < 4; ++s) { a[s][0] = RD_A(1, s, 0); a[s][1] = RD_A(1, s, 1); } \
    _Pragma("unroll") for (int s = 0; s < 2; ++s) { b[s][0] = RD_B(1, s, 0); b[s][1] = RD_B(1, s, 1); } \
    if (F == 1) STAGE_A(t + 2, 0, 0); else if (F == 2) STAGE_A_N(0, 0, 0);                      \
    asm volatile("s_waitcnt lgkmcnt(8)" ::: "memory");                                          \
    BARR(); LGKM0();                                                                            \
    __builtin_amdgcn_s_setprio(1); MM(0, 0); __builtin_amdgcn_s_setprio(0); BARR();             \
    _Pragma("unroll") for (int s = 2; s < 4; ++s) { b[s][0] = RD_B(1, s, 0); b[s][1] = RD_B(1, s, 1); } \
    if (F == 1) STAGE_A(t + 2, 0, 1); else if (F == 2) STAGE_A_N(0, 0, 1);                      \
    BARR(); LGKM0();                                                                            \
    __builtin_amdgcn_s_setprio(1); MM(0, 2); __builtin_amdgcn_s_setprio(0); BARR();             \
    _Pragma("unroll") for (int s = 0; s < 4; ++s) { a[s][0] = RD_A(1, 4 + s, 0); a[s][1] = RD_A(1, 4 + s, 1); } \
    if (F == 1) STAGE_B(t + 3, 1, 0); else if (F == 2) STAGE_B(0, 0, 0);                        \
    BARR(); LGKM0();                                                                            \
    __builtin_amdgcn_s_setprio(1); MM(4, 0); __builtin_amdgcn_s_setprio(0); BARR();             \
    if (F == 1) { STAGE_B(t + 3, 1, 1); asm volatile("s_waitcnt vmcnt(4)" ::: "memory"); }      \
    else if (F == 2) { STAGE_B(0, 0, 1); }                                                      \
    BARR();                                                                                     \
    __builtin_amdgcn_s_setprio(1); MM(4, 2); __builtin_amdgcn_s_setprio(0); BARR();             \
} while (0)

    const int nkt = K >> 6;
    const int niter = nkt >> 1;
    const int fr = (lane >> 4) * 4;
    const int fc = lane & 15;

    for (int mt = 0; mt < NT; ++mt) {
        const size_t m0  = ((size_t)(tg * NT + mt)) * 256;
        const size_t m0n = m0 + 256;

#pragma unroll
        for (int i = 0; i < 8; ++i)
#pragma unroll
            for (int j = 0; j < 4; ++j) acc[i][j] = (f32x4){0.f, 0.f, 0.f, 0.f};

        if (mt == 0) {
            STAGE_A(0, 0, 0);
            STAGE_A(0, 0, 1);
            STAGE_B(0, 0, 0);
            STAGE_B(0, 0, 1);
            STAGE_B(1, 1, 0);
            STAGE_B(1, 1, 1);
            asm volatile("s_waitcnt vmcnt(4)" ::: "memory");
            BARR();
        }

        for (int it = 0; it < niter; ++it) {
            const int t = 2 * it;
            const int F = (it + 1 < niter) ? 1 : ((mt + 1 < NT) ? 2 : 0);
            ITER(F);
        }

        // ---- epilogue: C/D layout col = lane&15, row = (lane>>4)*4 + r
        if constexpr (EPI == 0) {
            float2* qd = (float2*)(ldsc + 131072);  // [256 rows][4 quadrants] scratch
            const int wnq = w & 3;
            u16* C = (u16*)Cout;
#pragma unroll
            for (int mf = 0; mf < 8; ++mf)
#pragma unroll
                for (int r = 0; r < 4; ++r) {
                    const int lrow = wm + mf * 16 + fr + r;
                    const size_t row = m0 + lrow;
                    float s = 0.f, ss = 0.f;
#pragma unroll
                    for (int nf = 0; nf < 4; ++nf) {
                        float g = gelu_fast(acc[mf][nf][r]);
                        C[row * (size_t)N + (n0 + wn + nf * 16 + fc)] = f2b(g);
                        s += g;
                        ss = fmaf(g, g, ss);
                    }
                    s  = rowsum16(s);
                    ss = rowsum16(ss);
                    if (fc == 15) qd[lrow * 4 + wnq] = make_float2(s, ss);
                }
            LGKM0(); BARR();                        // LDS-only fence (keep loads in flight)
            if (tid < 256) {
                float2 q0 = qd[tid * 4 + 0], q1 = qd[tid * 4 + 1];
                float2 q2 = qd[tid * 4 + 2], q3 = qd[tid * 4 + 3];
                pS[(size_t)bx * MROWS + m0 + tid]  = (q0.x + q1.x) + (q2.x + q3.x);
                pSS[(size_t)bx * MROWS + m0 + tid] = (q0.y + q1.y) + (q2.y + q3.y);
            }
        } else {
            float* sA = (float*)(ldsc + 131072);    // [256] rstd
            float* sB = (float*)(ldsc + 132096);    // [256] -mu*rstd
            if (tid < 256) {
                float s = 0.f, ss = 0.f;
#pragma unroll
                for (int bq = 0; bq < 16; ++bq) {
                    s  += pS[(size_t)bq * MROWS + m0 + tid];
                    ss += pSS[(size_t)bq * MROWS + m0 + tid];
                }
                const float mu  = s * (1.f / (float)D_HID);
                const float var = ss * (1.f / (float)D_HID) - mu * mu;
                const float Av  = rsqrtf(var + 1e-5f);
                sA[tid] = Av;
                sB[tid] = -mu * Av;
            }
            LGKM0(); BARR();
            float* C = (float*)Cout;
            float c1v[4], c0v[4];
#pragma unroll
            for (int nf = 0; nf < 4; ++nf) {
                const size_t col = n0 + wn + nf * 16 + fc;
                c1v[nf] = c1t[col];
                c0v[nf] = c0t[col];
            }
#pragma unroll
            for (int mf = 0; mf < 8; ++mf)
#pragma unroll
                for (int r = 0; r < 4; ++r) {
                    const int lrow = wm + mf * 16 + fr + r;
                    const size_t row = m0 + lrow;
                    const float Av = sA[lrow], Bv = sB[lrow];
#pragma unroll
                    for (int nf = 0; nf < 4; ++nf) {
                        const size_t col = n0 + wn + nf * 16 + fc;
                        C[row * (size_t)N + col] = fmaf(Av, acc[mf][nf][r], fmaf(Bv, c1v[nf], c0v[nf]));
                    }
                }
        }

        if (mt + 1 < NT) {
            // finish next tile's prologue: B(1) -> buf1 (B-panel identical, L2-hot)
            STAGE_B(1, 1, 0);
            STAGE_B(1, 1, 1);
            asm volatile("s_waitcnt vmcnt(4)" ::: "memory");   // next tile0 fully staged
            BARR();
        }
    }
#undef STAGE_A
#undef STAGE_A_N
#undef STAGE_B
#undef RD_A
#undef RD_B
#undef MM
#undef BARR
#undef LGKM0
#undef ITER
}

extern "C" void kernel_launch(void* const* d_in, const int* in_sizes, int n_in,
                              void* d_out, int out_size, void* d_ws, size_t ws_size,
                              hipStream_t stream)
{
    const float* x   = (const float*)d_in[0];
    const float* Wfc = (const float*)d_in[1];
    const float* lnw = (const float*)d_in[2];
    const float* lnb = (const float*)d_in[3];
    const float* Wpj = (const float*)d_in[4];
    float* out = (float*)d_out;
    char* ws = (char*)d_ws;

    u16* Wq_fc = (u16*)ws;                                   // 8 MiB
    u16* Wq_pj = (u16*)(ws + (size_t)(8u  << 20));           // 8 MiB (scaled by lnw)
    u16* xb    = (u16*)(ws + (size_t)(16u << 20));           // 32 MiB
    u16* hbuf  = (u16*)(ws + (size_t)(48u << 20));           // 128 MiB (post-GELU, pre-LN)
    char* tail = ws + (size_t)(176u << 20);
    float* parts = (float*)tail;                             // 2 x 1024
    float* gam   = (float*)(tail + 8192);                    // 2
    float* c1t   = (float*)(tail + 16384);                   // 1024
    float* c0t   = (float*)(tail + 16384 + 4096);            // 1024
    float* pS    = (float*)(ws + (size_t)(177u << 20));      // 16 x 16384 (1 MiB)
    float* pSS   = (float*)(ws + (size_t)(178u << 20));      // 16 x 16384 (1 MiB)

    const int nW  = D_HID * D_IN;        // 4,194,304
    const int nW4 = nW / 4;
    const int nX8 = MROWS * D_IN / 8;    // 2,097,152

    // prep: absmean partials (y=0,1) + x->bf16 cast (y=2)
    prep1<<<dim3(1024, 3), 256, 0, stream>>>(x, Wfc, Wpj, xb, parts, nW4, nX8);
    absmean_finalize2<<<2, 256, 0, stream>>>(parts, 1.f / (float)nW, gam);
    // quant W_fc (y=0) + per-row quant W_proj*lnw with fused c1/c0 GEMV (y=1)
    prep2<<<dim3(1024, 2), 256, 0, stream>>>(Wfc, Wpj, lnw, lnb, gam, Wq_fc, Wq_pj, c1t, c0t, nW4);

    // GEMM1: [16384,1024] x [4096,1024]^T -> GELU -> bf16 + row stats partials
    // persistent: 256 blocks, each does 4 M-tiles at fixed bx
    {
        const int nbx = D_HID / 256;     // 16
        const int ntg = (MROWS / 256) / 4;  // 16 tile-groups
        gemm256<0, 4><<<dim3(nbx * ntg), dim3(512), 0, stream>>>(
            xb, Wq_fc, hbuf, MROWS, D_HID, D_IN, nbx, pS, pSS, nullptr, nullptr);
    }

    // GEMM2: [16384,4096] x [1024,4096]^T, LN fused (stats from pS/pSS) -> f32
    {
        const int nbx = D_IN / 256;      // 4
        const int nby = MROWS / 256;     // 64
        gemm256<1, 1><<<dim3(nbx * nby), dim3(512), 0, stream>>>(
            hbuf, Wq_pj, out, MROWS, D_IN, D_HID, nbx, pS, pSS, c1t, c0t);
    }
}